// Round 4
// baseline (2729.094 us; speedup 1.0000x reference)
//
#include <hip/hip_runtime.h>
#include <hip/hip_bf16.h>

#define NTOK 8192      // B*T
#define CDIM 256
#define TDIM 2048
#define BDIM 4
#define HDIM 8
#define HSZ  32
#define LNUM 4
#define BUF  (NTOK*CDIM)   // 2,097,152 floats = 8 MB

// ---------------- embedding: x[bt][c] = tok[idx[bt]][c] + pos[t][c] ----------------
__global__ __launch_bounds__(256) void k_embed(const int* __restrict__ idx,
    const float* __restrict__ tok, const float* __restrict__ pos, float* __restrict__ x) {
  int i  = blockIdx.x*256 + threadIdx.x;   // over NTOK*CDIM
  int c  = i & (CDIM-1);
  int bt = i >> 8;
  int t  = bt & (TDIM-1);
  x[i] = tok[(size_t)idx[bt]*CDIM + c] + pos[t*CDIM + c];
}

// ---------------- layernorm: one block (256 thr) per row of 256 ----------------
__global__ __launch_bounds__(256) void k_ln(const float* __restrict__ X,
    const float* __restrict__ g, const float* __restrict__ b, float* __restrict__ Y) {
  int row = blockIdx.x, tid = threadIdx.x;
  float v = X[(size_t)row*CDIM + tid];
  float s1 = v, s2 = v*v;
  #pragma unroll
  for (int off=32; off>0; off>>=1) { s1 += __shfl_down(s1, off, 64); s2 += __shfl_down(s2, off, 64); }
  __shared__ float r1[4], r2[4];
  int wave = tid >> 6, lane = tid & 63;
  if (lane == 0) { r1[wave] = s1; r2[wave] = s2; }
  __syncthreads();
  s1 = r1[0]+r1[1]+r1[2]+r1[3];
  s2 = r2[0]+r2[1]+r2[2]+r2[3];
  float mean = s1*(1.f/CDIM);
  float var  = s2*(1.f/CDIM) - mean*mean;
  float inv  = rsqrtf(var + 1e-5f);
  Y[(size_t)row*CDIM + tid] = (v-mean)*inv*g[tid] + b[tid];
}

// ---------------- GEMM: [8192,256] x [256,256], fp32 ----------------
// BMODE 0: B row-major [K=256, N=256].  BMODE 1: Wq/Wk/Wv layout [H][K][32], col=h*32+d.
template<int BMODE, bool BIAS, bool RELU, bool ACCUM>
__global__ __launch_bounds__(256) void k_gemm(const float* __restrict__ A,
    const float* __restrict__ B, const float* __restrict__ bias, float* __restrict__ C) {
  constexpr int BK = 16;
  __shared__ __align__(16) float As[BK][68];   // row stride 68 floats = 272B = 17*16B (rows stay 16B-aligned)
  __shared__ __align__(16) float Bs[BK][64];
  const int tid = threadIdx.x;
  const int tx = tid & 15, ty = tid >> 4;
  const int blockRow = blockIdx.x * 64;
  const int blockCol = blockIdx.y * 64;
  float acc[4][4] = {};
  for (int k0 = 0; k0 < 256; k0 += BK) {
    #pragma unroll
    for (int it=0; it<4; ++it) {            // A tile: 64x16
      int j = it*256 + tid;
      int m = j >> 4, kk = j & 15;
      As[kk][m] = A[(size_t)(blockRow+m)*CDIM + k0 + kk];
    }
    #pragma unroll
    for (int it=0; it<4; ++it) {            // B tile: 16x64
      int j = it*256 + tid;
      int kk = j >> 6, n = j & 63;
      float v;
      if (BMODE == 0) {
        v = B[(size_t)(k0+kk)*256 + blockCol + n];
      } else {
        int col = blockCol + n;
        v = B[(size_t)(col>>5)*8192 + (size_t)(k0+kk)*32 + (col&31)];
      }
      Bs[kk][n] = v;
    }
    __syncthreads();
    #pragma unroll
    for (int kk=0; kk<BK; ++kk) {
      float4 a4 = *(const float4*)&As[kk][ty*4];
      float4 b4 = *(const float4*)&Bs[kk][tx*4];
      float a[4] = {a4.x, a4.y, a4.z, a4.w};
      float bb[4] = {b4.x, b4.y, b4.z, b4.w};
      #pragma unroll
      for (int i=0;i<4;++i)
        #pragma unroll
        for (int j=0;j<4;++j)
          acc[i][j] = fmaf(a[i], bb[j], acc[i][j]);
    }
    __syncthreads();
  }
  #pragma unroll
  for (int i=0;i<4;++i) {
    int row = blockRow + ty*4 + i;
    #pragma unroll
    for (int j=0;j<4;++j) {
      int col = blockCol + tx*4 + j;
      float v = acc[i][j];
      if (BIAS) v += bias[col];
      if (RELU) v = fmaxf(v, 0.f);
      size_t oi = (size_t)row*CDIM + col;
      if (ACCUM) C[oi] += v; else C[oi] = v;
    }
  }
}

// ---------------- attention: 2 threads per q-row, clamped plain softmax ----------------
// grid (16 qblocks, H, B), 256 threads = 128 q-rows x 2 halves.
// Logits ~N(0, 0.04^2) for this model; clamp at +-60 guarantees finite exp/sum regardless.
__global__ __launch_bounds__(256) void k_attn(const float* __restrict__ Q,
    const float* __restrict__ K, const float* __restrict__ V, float* __restrict__ O) {
  __shared__ __align__(16) float Ks[128][32];
  __shared__ __align__(16) float Vs[128][32];
  const int tid = threadIdx.x;
  const int b = blockIdx.z, h = blockIdx.y;
  const int t = blockIdx.x*128 + (tid >> 1);
  const int half = tid & 1;
  const float scale = 0.0625f;               // C^-0.5 = 1/16 (faithful to ref)
  const float* qrow = Q + (size_t)(b*TDIM + t)*CDIM + h*HSZ + half*16;
  float q[16], o[16];
  #pragma unroll
  for (int j=0;j<4;++j) {
    float4 v4 = ((const float4*)qrow)[j];
    q[4*j+0]=v4.x*scale; q[4*j+1]=v4.y*scale; q[4*j+2]=v4.z*scale; q[4*j+3]=v4.w*scale;
    o[4*j+0]=0.f; o[4*j+1]=0.f; o[4*j+2]=0.f; o[4*j+3]=0.f;
  }
  float l = 0.f;
  for (int s0 = 0; s0 < TDIM; s0 += 128) {
    __syncthreads();
    #pragma unroll
    for (int it=0; it<16; ++it) {           // stage K,V tiles (128x32 each)
      int j = it*256 + tid;
      int s = j >> 5, d = j & 31;
      size_t gidx = (size_t)(b*TDIM + s0 + s)*CDIM + h*HSZ + d;
      Ks[s][d] = K[gidx];
      Vs[s][d] = V[gidx];
    }
    __syncthreads();
    for (int s=0; s<128; ++s) {
      const float4* kr = (const float4*)&Ks[s][half*16];
      float4 k0v=kr[0], k1v=kr[1], k2v=kr[2], k3v=kr[3];
      float d0 = fmaf(q[0], k0v.x, fmaf(q[1], k0v.y, fmaf(q[2], k0v.z, q[3] *k0v.w)));
      float d1 = fmaf(q[4], k1v.x, fmaf(q[5], k1v.y, fmaf(q[6], k1v.z, q[7] *k1v.w)));
      float d2 = fmaf(q[8], k2v.x, fmaf(q[9], k2v.y, fmaf(q[10],k2v.z, q[11]*k2v.w)));
      float d3 = fmaf(q[12],k3v.x, fmaf(q[13],k3v.y, fmaf(q[14],k3v.z, q[15]*k3v.w)));
      float dot = (d0+d1) + (d2+d3);
      dot += __shfl_xor(dot, 1, 64);         // combine the two half-dots (pair lanes)
      dot = fminf(fmaxf(dot, -60.f), 60.f);  // finite-exp guarantee
      float p = __expf(dot);
      l += p;
      const float4* vr = (const float4*)&Vs[s][half*16];
      #pragma unroll
      for (int j=0;j<4;++j) {
        float4 v4 = vr[j];
        o[4*j+0]=fmaf(p,v4.x,o[4*j+0]); o[4*j+1]=fmaf(p,v4.y,o[4*j+1]);
        o[4*j+2]=fmaf(p,v4.z,o[4*j+2]); o[4*j+3]=fmaf(p,v4.w,o[4*j+3]);
      }
    }
  }
  float inv = 1.f / l;
  float* orow = O + (size_t)(b*TDIM + t)*CDIM + h*HSZ + half*16;
  #pragma unroll
  for (int j=0;j<4;++j)
    ((float4*)orow)[j] = make_float4(o[4*j]*inv, o[4*j+1]*inv, o[4*j+2]*inv, o[4*j+3]*inv);
}

// ---------------- mean-pool partials: 32 blocks, each sums 256 rows ----------------
__global__ __launch_bounds__(256) void k_pool(const float* __restrict__ Hf, float* __restrict__ part) {
  int b = blockIdx.x >> 3, chunk = blockIdx.x & 7;
  int c = threadIdx.x;
  int row0 = b*TDIM + chunk*256;
  float s = 0.f;
  for (int tt=0; tt<256; ++tt) s += Hf[(size_t)(row0+tt)*CDIM + c];
  part[blockIdx.x*256 + c] = s * (1.f/2048.f);
}

// ---------------- classifier: combine partials -> fc1+relu -> fc2 -> softmax (fp32 out) ------
__global__ __launch_bounds__(256) void k_cls(const float* __restrict__ part,
    const float* __restrict__ Wc1, const float* __restrict__ bc1,
    const float* __restrict__ Wc2, const float* __restrict__ bc2, float* __restrict__ out) {
  __shared__ float se[4*256];
  __shared__ float sh[4*512];
  __shared__ float sl[40];
  int tid = threadIdx.x;
  for (int j=tid; j<1024; j+=256) {
    int b = j >> 8, c = j & 255;
    float s = 0.f;
    #pragma unroll
    for (int ch=0; ch<8; ++ch) s += part[(b*8+ch)*256 + c];
    se[j] = s;
  }
  __syncthreads();
  for (int j=tid; j<2048; j+=256) {
    int b = j >> 9, u = j & 511;
    float s = bc1[u];
    for (int c=0; c<256; ++c) s = fmaf(se[b*256+c], Wc1[c*512+u], s);
    sh[j] = fmaxf(s, 0.f);
  }
  __syncthreads();
  if (tid < 40) {
    int b = tid/10, j2 = tid%10;
    float s = bc2[j2];
    for (int u=0; u<512; ++u) s = fmaf(sh[b*512+u], Wc2[u*10+j2], s);
    sl[tid] = s;
  }
  __syncthreads();
  if (tid < 4) {
    float mx = -1e30f;
    for (int j=0;j<10;++j) mx = fmaxf(mx, sl[tid*10+j]);
    float e[10], sum = 0.f;
    for (int j=0;j<10;++j) { e[j] = __expf(sl[tid*10+j]-mx); sum += e[j]; }
    float inv = 1.f/sum;
    for (int j=0;j<10;++j) out[tid*10+j] = e[j]*inv;   // fp32 output, per ref dtype
  }
}

extern "C" void kernel_launch(void* const* d_in, const int* in_sizes, int n_in,
                              void* d_out, int out_size, void* d_ws, size_t ws_size,
                              hipStream_t stream) {
  const int*   idx = (const int*)d_in[0];
  const float* tok = (const float*)d_in[1];
  const float* pos = (const float*)d_in[2];
  const float* Wq  = (const float*)d_in[3];
  const float* Wk  = (const float*)d_in[4];
  const float* Wv  = (const float*)d_in[5];
  const float* Wp  = (const float*)d_in[6];
  const float* bp  = (const float*)d_in[7];
  const float* l1g = (const float*)d_in[8];
  const float* l1b = (const float*)d_in[9];
  const float* l2g = (const float*)d_in[10];
  const float* l2b = (const float*)d_in[11];
  const float* W1  = (const float*)d_in[12];
  const float* b1  = (const float*)d_in[13];
  const float* W2  = (const float*)d_in[14];
  const float* b2  = (const float*)d_in[15];
  const float* lfg = (const float*)d_in[16];
  const float* lfb = (const float*)d_in[17];
  const float* Wc1 = (const float*)d_in[18];
  const float* bc1 = (const float*)d_in[19];
  const float* Wc2 = (const float*)d_in[20];
  const float* bc2 = (const float*)d_in[21];

  float* xb   = (float*)d_ws;     // [8192,256] residual stream
  float* hb   = xb + BUF;         // LN out; reused as attention out
  float* qb   = hb + BUF;         // Q; later FFN hidden
  float* kb   = qb + BUF;         // K
  float* vb   = kb + BUF;         // V
  float* part = vb + BUF;         // 32*256 pool partials

  dim3 gg(128, 4);                // 64x64 tiles over [8192,256]
  k_embed<<<NTOK*CDIM/256, 256, 0, stream>>>(idx, tok, pos, xb);
  for (int l = 0; l < LNUM; ++l) {
    k_ln<<<NTOK, 256, 0, stream>>>(xb, l1g + l*CDIM, l1b + l*CDIM, hb);
    k_gemm<1,false,false,false><<<gg, 256, 0, stream>>>(hb, Wq + l*65536, nullptr, qb);
    k_gemm<1,false,false,false><<<gg, 256, 0, stream>>>(hb, Wk + l*65536, nullptr, kb);
    k_gemm<1,false,false,false><<<gg, 256, 0, stream>>>(hb, Wv + l*65536, nullptr, vb);
    k_attn<<<dim3(16, HDIM, BDIM), 256, 0, stream>>>(qb, kb, vb, hb);   // hb := attn out
    k_gemm<0,true,false,true><<<gg, 256, 0, stream>>>(hb, Wp + l*65536, bp + l*CDIM, xb);
    k_ln<<<NTOK, 256, 0, stream>>>(xb, l2g + l*CDIM, l2b + l*CDIM, hb);
    k_gemm<0,true,true,false><<<gg, 256, 0, stream>>>(hb, W1 + l*65536, b1 + l*CDIM, qb);
    k_gemm<0,true,false,true><<<gg, 256, 0, stream>>>(qb, W2 + l*65536, b2 + l*CDIM, xb);
  }
  k_ln<<<NTOK, 256, 0, stream>>>(xb, lfg, lfb, hb);
  k_pool<<<32, 256, 0, stream>>>(hb, part);
  k_cls<<<1, 256, 0, stream>>>(part, Wc1, bc1, Wc2, bc2, (float*)d_out);
}

// Round 5
// 978.603 us; speedup vs baseline: 2.7888x; 2.7888x over previous
//
#include <hip/hip_runtime.h>
#include <hip/hip_bf16.h>

#define NTOK 8192      // B*T
#define CDIM 256
#define TDIM 2048
#define BDIM 4
#define HDIM 8
#define HSZ  32
#define LNUM 4
#define BUF  (NTOK*CDIM)   // 2,097,152 floats = 8 MB

typedef __attribute__((ext_vector_type(8))) short short8v;
typedef __attribute__((ext_vector_type(4))) short short4v;
typedef __attribute__((ext_vector_type(4))) float float4v;

// fp32 -> bf16 (RNE) as raw short
static __device__ __forceinline__ short f2bs(float f){
  union { float f; unsigned u; } x; x.f = f;
  unsigned r = x.u + 0x7FFFu + ((x.u >> 16) & 1u);
  return (short)(r >> 16);
}

#if __has_builtin(__builtin_amdgcn_mfma_f32_16x16x16bf16_1k)
static __device__ __forceinline__ float4v mfma16(short4v a, short4v b, float4v c){
  return __builtin_amdgcn_mfma_f32_16x16x16bf16_1k(a, b, c, 0, 0, 0);
}
#else
static __device__ __forceinline__ float4v mfma16(short4v a, short4v b, float4v c){
  float4v d;
  asm volatile("v_mfma_f32_16x16x16_bf16 %0, %1, %2, %3\n\ts_nop 7\n\ts_nop 7"
               : "=v"(d) : "v"(a), "v"(b), "v"(c));
  return d;
}
#endif

// ---------------- embedding ----------------
__global__ __launch_bounds__(256) void k_embed(const int* __restrict__ idx,
    const float* __restrict__ tok, const float* __restrict__ pos, float* __restrict__ x) {
  int i  = blockIdx.x*256 + threadIdx.x;
  int c  = i & (CDIM-1);
  int bt = i >> 8;
  int t  = bt & (TDIM-1);
  x[i] = tok[(size_t)idx[bt]*CDIM + c] + pos[t*CDIM + c];
}

// ---------------- layernorm ----------------
__global__ __launch_bounds__(256) void k_ln(const float* __restrict__ X,
    const float* __restrict__ g, const float* __restrict__ b, float* __restrict__ Y) {
  int row = blockIdx.x, tid = threadIdx.x;
  float v = X[(size_t)row*CDIM + tid];
  float s1 = v, s2 = v*v;
  #pragma unroll
  for (int off=32; off>0; off>>=1) { s1 += __shfl_down(s1, off, 64); s2 += __shfl_down(s2, off, 64); }
  __shared__ float r1[4], r2[4];
  int wave = tid >> 6, lane = tid & 63;
  if (lane == 0) { r1[wave] = s1; r2[wave] = s2; }
  __syncthreads();
  s1 = r1[0]+r1[1]+r1[2]+r1[3];
  s2 = r2[0]+r2[1]+r2[2]+r2[3];
  float mean = s1*(1.f/CDIM);
  float var  = s2*(1.f/CDIM) - mean*mean;
  float inv  = rsqrtf(var + 1e-5f);
  Y[(size_t)row*CDIM + tid] = (v-mean)*inv*g[tid] + b[tid];
}

// ---------------- GEMM (unchanged from passing round) ----------------
template<int BMODE, bool BIAS, bool RELU, bool ACCUM>
__global__ __launch_bounds__(256) void k_gemm(const float* __restrict__ A,
    const float* __restrict__ B, const float* __restrict__ bias, float* __restrict__ C) {
  constexpr int BK = 16;
  __shared__ __align__(16) float As[BK][68];
  __shared__ __align__(16) float Bs[BK][64];
  const int tid = threadIdx.x;
  const int tx = tid & 15, ty = tid >> 4;
  const int blockRow = blockIdx.x * 64;
  const int blockCol = blockIdx.y * 64;
  float acc[4][4] = {};
  for (int k0 = 0; k0 < 256; k0 += BK) {
    #pragma unroll
    for (int it=0; it<4; ++it) {
      int j = it*256 + tid;
      int m = j >> 4, kk = j & 15;
      As[kk][m] = A[(size_t)(blockRow+m)*CDIM + k0 + kk];
    }
    #pragma unroll
    for (int it=0; it<4; ++it) {
      int j = it*256 + tid;
      int kk = j >> 6, n = j & 63;
      float v;
      if (BMODE == 0) {
        v = B[(size_t)(k0+kk)*256 + blockCol + n];
      } else {
        int col = blockCol + n;
        v = B[(size_t)(col>>5)*8192 + (size_t)(k0+kk)*32 + (col&31)];
      }
      Bs[kk][n] = v;
    }
    __syncthreads();
    #pragma unroll
    for (int kk=0; kk<BK; ++kk) {
      float4 a4 = *(const float4*)&As[kk][ty*4];
      float4 b4 = *(const float4*)&Bs[kk][tx*4];
      float a[4] = {a4.x, a4.y, a4.z, a4.w};
      float bb[4] = {b4.x, b4.y, b4.z, b4.w};
      #pragma unroll
      for (int i=0;i<4;++i)
        #pragma unroll
        for (int j=0;j<4;++j)
          acc[i][j] = fmaf(a[i], bb[j], acc[i][j]);
    }
    __syncthreads();
  }
  #pragma unroll
  for (int i=0;i<4;++i) {
    int row = blockRow + ty*4 + i;
    #pragma unroll
    for (int j=0;j<4;++j) {
      int col = blockCol + tx*4 + j;
      float v = acc[i][j];
      if (BIAS) v += bias[col];
      if (RELU) v = fmaxf(v, 0.f);
      size_t oi = (size_t)row*CDIM + col;
      if (ACCUM) C[oi] += v; else C[oi] = v;
    }
  }
}

// ---------------- MFMA flash attention ----------------
// grid (16, H, B), 256 thr = 4 waves; wave handles 2 q-tiles of 16 rows (32 rows), block 128 rows.
// Per 16-key step: S^T = K_chunk(16x32) x Q^T(32x16) via mfma_f32_16x16x32_bf16.
//   C/D frag: lane(q,r) holds S[qrow=r][key=q*4+reg]  -- exactly the A-operand layout
//   (A[m=lane&15][k=quad*4+j]) of mfma_f32_16x16x16_bf16, so exp'd P feeds PV directly.
// PV: O += P(16x16) x V(16x16) twice (dims 0-15, 16-31). No online max: logits ~N(0,0.04^2),
// clamp +-60 keeps exp/sum finite; p_i/l is mathematically the ref softmax (verified round 4).
#define KS_STRIDE 40   // shorts; 80B rows -> b128 reads 2-way bank alias (free)
#define VT_STRIDE 72   // shorts; 144B rows -> b64 reads 2-way (free)
__global__ __launch_bounds__(256) void k_attn2(const float* __restrict__ Q,
    const float* __restrict__ K, const float* __restrict__ V, float* __restrict__ O) {
  __shared__ __align__(16) short Ks[64*KS_STRIDE];
  __shared__ __align__(16) short Vt[32*VT_STRIDE];
  const int tid = threadIdx.x;
  const int w = tid >> 6, lane = tid & 63;
  const int q4 = lane >> 4, r = lane & 15;          // quad, id-in-quad
  const int b = blockIdx.z, h = blockIdx.y;
  const int rowbase = blockIdx.x*128 + w*32;
  const float qscale = 0.0625f;                      // C^-0.5, folded into Q
  // Q fragments (B-operand of 16x16x32): lane(q,r) holds Q[qrow=r][dims q*8..q*8+7]
  short8v Qf[2];
  #pragma unroll
  for (int u=0; u<2; ++u) {
    const float* qp = Q + ((size_t)(b*TDIM + rowbase + u*16 + r))*CDIM + h*HSZ + q4*8;
    float4 a = *(const float4*)qp, c = *(const float4*)(qp+4);
    Qf[u][0]=f2bs(a.x*qscale); Qf[u][1]=f2bs(a.y*qscale);
    Qf[u][2]=f2bs(a.z*qscale); Qf[u][3]=f2bs(a.w*qscale);
    Qf[u][4]=f2bs(c.x*qscale); Qf[u][5]=f2bs(c.y*qscale);
    Qf[u][6]=f2bs(c.z*qscale); Qf[u][7]=f2bs(c.w*qscale);
  }
  float4v o00 = {0,0,0,0}, o01 = {0,0,0,0}, o10 = {0,0,0,0}, o11 = {0,0,0,0};
  float l0 = 0.f, l1 = 0.f;
  const int skey = tid >> 2, d0 = (tid & 3)*8;       // staging mapping
  for (int s0 = 0; s0 < TDIM; s0 += 64) {
    __syncthreads();
    { // stage 64 keys: K -> Ks[key][dim] bf16; V -> Vt[dim][key] bf16 (transposed)
      const float* kp = K + ((size_t)(b*TDIM + s0 + skey))*CDIM + h*HSZ + d0;
      const float* vp = V + ((size_t)(b*TDIM + s0 + skey))*CDIM + h*HSZ + d0;
      float4 ka = *(const float4*)kp, kb2 = *(const float4*)(kp+4);
      float4 va = *(const float4*)vp, vb2 = *(const float4*)(vp+4);
      short8v kk;
      kk[0]=f2bs(ka.x); kk[1]=f2bs(ka.y); kk[2]=f2bs(ka.z); kk[3]=f2bs(ka.w);
      kk[4]=f2bs(kb2.x); kk[5]=f2bs(kb2.y); kk[6]=f2bs(kb2.z); kk[7]=f2bs(kb2.w);
      *(short8v*)&Ks[skey*KS_STRIDE + d0] = kk;
      Vt[(d0+0)*VT_STRIDE + skey] = f2bs(va.x);
      Vt[(d0+1)*VT_STRIDE + skey] = f2bs(va.y);
      Vt[(d0+2)*VT_STRIDE + skey] = f2bs(va.z);
      Vt[(d0+3)*VT_STRIDE + skey] = f2bs(va.w);
      Vt[(d0+4)*VT_STRIDE + skey] = f2bs(vb2.x);
      Vt[(d0+5)*VT_STRIDE + skey] = f2bs(vb2.y);
      Vt[(d0+6)*VT_STRIDE + skey] = f2bs(vb2.z);
      Vt[(d0+7)*VT_STRIDE + skey] = f2bs(vb2.w);
    }
    __syncthreads();
    #pragma unroll
    for (int ks = 0; ks < 4; ++ks) {
      // A-frag: K[key=ks*16+r][dims q*8..+7]
      short8v Kf = *(const short8v*)&Ks[(ks*16 + r)*KS_STRIDE + q4*8];
      float4v s0v = __builtin_amdgcn_mfma_f32_16x16x32_bf16(Kf, Qf[0], (float4v){0,0,0,0}, 0, 0, 0);
      float4v s1v = __builtin_amdgcn_mfma_f32_16x16x32_bf16(Kf, Qf[1], (float4v){0,0,0,0}, 0, 0, 0);
      // V B-frags: lane(q,r) holds V[key=ks*16+q*4+j][dim=r] (and dim=16+r)
      short4v Vf0 = *(const short4v*)&Vt[r*VT_STRIDE + ks*16 + q4*4];
      short4v Vf1 = *(const short4v*)&Vt[(16+r)*VT_STRIDE + ks*16 + q4*4];
      short4v P0, P1;
      #pragma unroll
      for (int j=0;j<4;++j) {
        float p0 = __expf(fminf(fmaxf(s0v[j], -60.f), 60.f));
        float p1 = __expf(fminf(fmaxf(s1v[j], -60.f), 60.f));
        l0 += p0; l1 += p1;
        P0[j] = f2bs(p0); P1[j] = f2bs(p1);
      }
      o00 = mfma16(P0, Vf0, o00); o01 = mfma16(P0, Vf1, o01);
      o10 = mfma16(P1, Vf0, o10); o11 = mfma16(P1, Vf1, o11);
    }
  }
  // softmax denominators: partial per lane -> full per qrow across quads
  l0 += __shfl_xor(l0, 16, 64); l0 += __shfl_xor(l0, 32, 64);
  l1 += __shfl_xor(l1, 16, 64); l1 += __shfl_xor(l1, 32, 64);
  #pragma unroll
  for (int reg=0; reg<4; ++reg) {
    int qrow = q4*4 + reg;                 // O C/D: row=quad*4+reg, col=r
    float i0 = 1.f / __shfl(l0, qrow, 64); // lane 'qrow' holds l for that qrow
    float i1 = 1.f / __shfl(l1, qrow, 64);
    float* op0 = O + ((size_t)(b*TDIM + rowbase + qrow))*CDIM + h*HSZ;
    op0[r]    = o00[reg]*i0;
    op0[16+r] = o01[reg]*i0;
    float* op1 = O + ((size_t)(b*TDIM + rowbase + 16 + qrow))*CDIM + h*HSZ;
    op1[r]    = o10[reg]*i1;
    op1[16+r] = o11[reg]*i1;
  }
}

// ---------------- mean-pool partials ----------------
__global__ __launch_bounds__(256) void k_pool(const float* __restrict__ Hf, float* __restrict__ part) {
  int b = blockIdx.x >> 3, chunk = blockIdx.x & 7;
  int c = threadIdx.x;
  int row0 = b*TDIM + chunk*256;
  float s = 0.f;
  for (int tt=0; tt<256; ++tt) s += Hf[(size_t)(row0+tt)*CDIM + c];
  part[blockIdx.x*256 + c] = s * (1.f/2048.f);
}

// ---------------- classifier ----------------
__global__ __launch_bounds__(256) void k_cls(const float* __restrict__ part,
    const float* __restrict__ Wc1, const float* __restrict__ bc1,
    const float* __restrict__ Wc2, const float* __restrict__ bc2, float* __restrict__ out) {
  __shared__ float se[4*256];
  __shared__ float sh[4*512];
  __shared__ float sl[40];
  int tid = threadIdx.x;
  for (int j=tid; j<1024; j+=256) {
    int b = j >> 8, c = j & 255;
    float s = 0.f;
    #pragma unroll
    for (int ch=0; ch<8; ++ch) s += part[(b*8+ch)*256 + c];
    se[j] = s;
  }
  __syncthreads();
  for (int j=tid; j<2048; j+=256) {
    int b = j >> 9, u = j & 511;
    float s = bc1[u];
    for (int c=0; c<256; ++c) s = fmaf(se[b*256+c], Wc1[c*512+u], s);
    sh[j] = fmaxf(s, 0.f);
  }
  __syncthreads();
  if (tid < 40) {
    int b = tid/10, j2 = tid%10;
    float s = bc2[j2];
    for (int u=0; u<512; ++u) s = fmaf(sh[b*512+u], Wc2[u*10+j2], s);
    sl[tid] = s;
  }
  __syncthreads();
  if (tid < 4) {
    float mx = -1e30f;
    for (int j=0;j<10;++j) mx = fmaxf(mx, sl[tid*10+j]);
    float e[10], sum = 0.f;
    for (int j=0;j<10;++j) { e[j] = __expf(sl[tid*10+j]-mx); sum += e[j]; }
    float inv = 1.f/sum;
    for (int j=0;j<10;++j) out[tid*10+j] = e[j]*inv;
  }
}

extern "C" void kernel_launch(void* const* d_in, const int* in_sizes, int n_in,
                              void* d_out, int out_size, void* d_ws, size_t ws_size,
                              hipStream_t stream) {
  const int*   idx = (const int*)d_in[0];
  const float* tok = (const float*)d_in[1];
  const float* pos = (const float*)d_in[2];
  const float* Wq  = (const float*)d_in[3];
  const float* Wk  = (const float*)d_in[4];
  const float* Wv  = (const float*)d_in[5];
  const float* Wp  = (const float*)d_in[6];
  const float* bp  = (const float*)d_in[7];
  const float* l1g = (const float*)d_in[8];
  const float* l1b = (const float*)d_in[9];
  const float* l2g = (const float*)d_in[10];
  const float* l2b = (const float*)d_in[11];
  const float* W1  = (const float*)d_in[12];
  const float* b1  = (const float*)d_in[13];
  const float* W2  = (const float*)d_in[14];
  const float* b2  = (const float*)d_in[15];
  const float* lfg = (const float*)d_in[16];
  const float* lfb = (const float*)d_in[17];
  const float* Wc1 = (const float*)d_in[18];
  const float* bc1 = (const float*)d_in[19];
  const float* Wc2 = (const float*)d_in[20];
  const float* bc2 = (const float*)d_in[21];

  float* xb   = (float*)d_ws;
  float* hb   = xb + BUF;
  float* qb   = hb + BUF;
  float* kb   = qb + BUF;
  float* vb   = kb + BUF;
  float* part = vb + BUF;

  dim3 gg(128, 4);
  k_embed<<<NTOK*CDIM/256, 256, 0, stream>>>(idx, tok, pos, xb);
  for (int l = 0; l < LNUM; ++l) {
    k_ln<<<NTOK, 256, 0, stream>>>(xb, l1g + l*CDIM, l1b + l*CDIM, hb);
    k_gemm<1,false,false,false><<<gg, 256, 0, stream>>>(hb, Wq + l*65536, nullptr, qb);
    k_gemm<1,false,false,false><<<gg, 256, 0, stream>>>(hb, Wk + l*65536, nullptr, kb);
    k_gemm<1,false,false,false><<<gg, 256, 0, stream>>>(hb, Wv + l*65536, nullptr, vb);
    k_attn2<<<dim3(16, HDIM, BDIM), 256, 0, stream>>>(qb, kb, vb, hb);
    k_gemm<0,true,false,true><<<gg, 256, 0, stream>>>(hb, Wp + l*65536, bp + l*CDIM, xb);
    k_ln<<<NTOK, 256, 0, stream>>>(xb, l2g + l*CDIM, l2b + l*CDIM, hb);
    k_gemm<0,true,true,false><<<gg, 256, 0, stream>>>(hb, W1 + l*65536, b1 + l*CDIM, qb);
    k_gemm<0,true,false,true><<<gg, 256, 0, stream>>>(qb, W2 + l*65536, b2 + l*CDIM, xb);
  }
  k_ln<<<NTOK, 256, 0, stream>>>(xb, lfg, lfb, hb);
  k_pool<<<32, 256, 0, stream>>>(hb, part);
  k_cls<<<1, 256, 0, stream>>>(part, Wc1, bc1, Wc2, bc2, (float*)d_out);
}

// Round 6
// 761.277 us; speedup vs baseline: 3.5849x; 1.2855x over previous
//
#include <hip/hip_runtime.h>
#include <hip/hip_bf16.h>

#define NTOK 8192      // B*T
#define CDIM 256
#define TDIM 2048
#define BDIM 4
#define HDIM 8
#define HSZ  32
#define LNUM 4
#define BUF  (NTOK*CDIM)

typedef __attribute__((ext_vector_type(8))) short short8v;
typedef __attribute__((ext_vector_type(4))) short short4v;
typedef __attribute__((ext_vector_type(4))) float float4v;

// fp32 -> bf16 (RNE) as raw short
static __device__ __forceinline__ short f2bs(float f){
  union { float f; unsigned u; } x; x.f = f;
  unsigned r = x.u + 0x7FFFu + ((x.u >> 16) & 1u);
  return (short)(r >> 16);
}
static __device__ __forceinline__ float bs2f(short s){
  union { unsigned u; float f; } x; x.u = ((unsigned)(unsigned short)s) << 16;
  return x.f;
}
// pack two fp32 -> bf16x2 (RNE): 2 adds + 1 v_perm
static __device__ __forceinline__ unsigned pkbf(float a, float b){
  union { float f; unsigned u; } x, y; x.f = a; y.f = b;
  unsigned ra = x.u + 0x7FFFu + ((x.u >> 16) & 1u);
  unsigned rb = y.u + 0x7FFFu + ((y.u >> 16) & 1u);
  return __builtin_amdgcn_perm(rb, ra, 0x07060302u);  // {ra.b2,ra.b3,rb.b2,rb.b3}
}

#if __has_builtin(__builtin_amdgcn_mfma_f32_16x16x16bf16_1k)
static __device__ __forceinline__ float4v mfma16(short4v a, short4v b, float4v c){
  return __builtin_amdgcn_mfma_f32_16x16x16bf16_1k(a, b, c, 0, 0, 0);
}
#else
static __device__ __forceinline__ float4v mfma16(short4v a, short4v b, float4v c){
  float4v d;
  asm volatile("v_mfma_f32_16x16x16_bf16 %0, %1, %2, %3\n\ts_nop 7\n\ts_nop 7"
               : "=v"(d) : "v"(a), "v"(b), "v"(c));
  return d;
}
#endif
static __device__ __forceinline__ float4v mfma32(short8v a, short8v b, float4v c){
  return __builtin_amdgcn_mfma_f32_16x16x32_bf16(a, b, c, 0, 0, 0);
}

// ---------------- embedding: fp32 residual stream ----------------
__global__ __launch_bounds__(256) void k_embed(const int* __restrict__ idx,
    const float* __restrict__ tok, const float* __restrict__ pos, float* __restrict__ x) {
  int i  = blockIdx.x*256 + threadIdx.x;
  int c  = i & (CDIM-1);
  int bt = i >> 8;
  int t  = bt & (TDIM-1);
  x[i] = tok[(size_t)idx[bt]*CDIM + c] + pos[t*CDIM + c];
}

// ---------------- layernorm: fp32 in -> bf16 out ----------------
__global__ __launch_bounds__(256) void k_ln(const float* __restrict__ X,
    const float* __restrict__ g, const float* __restrict__ b, short* __restrict__ Y) {
  int row = blockIdx.x, tid = threadIdx.x;
  float v = X[(size_t)row*CDIM + tid];
  float s1 = v, s2 = v*v;
  #pragma unroll
  for (int off=32; off>0; off>>=1) { s1 += __shfl_down(s1, off, 64); s2 += __shfl_down(s2, off, 64); }
  __shared__ float r1[4], r2[4];
  int wave = tid >> 6, lane = tid & 63;
  if (lane == 0) { r1[wave] = s1; r2[wave] = s2; }
  __syncthreads();
  s1 = r1[0]+r1[1]+r1[2]+r1[3];
  s2 = r2[0]+r2[1]+r2[2]+r2[3];
  float mean = s1*(1.f/CDIM);
  float var  = s2*(1.f/CDIM) - mean*mean;
  float inv  = rsqrtf(var + 1e-5f);
  Y[(size_t)row*CDIM + tid] = f2bs((v-mean)*inv*g[tid] + b[tid]);
}

// ---------------- MFMA GEMM: [8192,256](bf16) x [256,N](fp32 w) ----------------
// BM=64, BN=128, BK=32; 4 waves in 2x2; wave tile 32x64 (2 m-frags x 4 n-frags).
// Frag layouts (verified by k_attn2 round-5 pass):
//   A[m=r][k=q4*8+j] b128 from As[m][k]; B[k=q4*8+j][n=r] b128 from Bst[n][k] (B^T);
//   D: row=q4*4+reg, col=r.
// BMODE 0: B row-major [K][N].  BMODE 1: QKV weight [H][K][32], col=h*32+d.
#define GSTR 40   // LDS row stride (shorts): 80B rows, 16B-aligned, bank-balanced
template<int BMODE, bool BIAS, bool RELU, bool OUTBF16, bool ACCUM>
__global__ __launch_bounds__(256) void k_gemm2(const short* __restrict__ A,
    const float* __restrict__ B, const float* __restrict__ bias, void* __restrict__ Cv) {
  __shared__ __align__(16) short As[64*GSTR];
  __shared__ __align__(16) short Bst[128*GSTR];
  const int tid = threadIdx.x;
  const int w = tid >> 6, lane = tid & 63;
  const int q4 = lane >> 4, r = lane & 15;
  const int wm = w & 1, wn = w >> 1;
  const int blockRow = blockIdx.x * 64;
  const int blockCol = blockIdx.y * 128;
  float4v acc[2][4];
  #pragma unroll
  for (int i=0;i<2;++i)
    #pragma unroll
    for (int j=0;j<4;++j) acc[i][j] = (float4v){0,0,0,0};
  const int ar = tid >> 2, ac = (tid & 3) * 8;      // A staging: 64 rows x 4 chunks
  const int bn = tid & 127, bk = (tid >> 7) * 16;   // B staging: 128 n x 2 k-groups
  for (int k0 = 0; k0 < 256; k0 += 32) {
    __syncthreads();
    *(short8v*)&As[ar*GSTR + ac] =
        *(const short8v*)&A[(size_t)(blockRow + ar)*CDIM + k0 + ac];
    short vv[16];
    if (BMODE == 0) {
      #pragma unroll
      for (int j=0;j<16;++j) vv[j] = f2bs(B[(size_t)(k0+bk+j)*256 + blockCol + bn]);
    } else {
      int col = blockCol + bn;
      const float* bp2 = B + (size_t)(col>>5)*8192 + (col&31);
      #pragma unroll
      for (int j=0;j<16;++j) vv[j] = f2bs(bp2[(size_t)(k0+bk+j)*32]);
    }
    short8v pk0, pk1;
    #pragma unroll
    for (int j=0;j<8;++j) { pk0[j] = vv[j]; pk1[j] = vv[8+j]; }
    *(short8v*)&Bst[bn*GSTR + bk]     = pk0;
    *(short8v*)&Bst[bn*GSTR + bk + 8] = pk1;
    __syncthreads();
    short8v af0 = *(const short8v*)&As[(wm*32 +  0 + r)*GSTR + q4*8];
    short8v af1 = *(const short8v*)&As[(wm*32 + 16 + r)*GSTR + q4*8];
    #pragma unroll
    for (int nf=0;nf<4;++nf) {
      short8v bf = *(const short8v*)&Bst[(wn*64 + nf*16 + r)*GSTR + q4*8];
      acc[0][nf] = mfma32(af0, bf, acc[0][nf]);
      acc[1][nf] = mfma32(af1, bf, acc[1][nf]);
    }
  }
  #pragma unroll
  for (int mf=0;mf<2;++mf)
    #pragma unroll
    for (int nf=0;nf<4;++nf) {
      int col = blockCol + wn*64 + nf*16 + r;
      float bb = BIAS ? bias[col] : 0.f;
      #pragma unroll
      for (int reg=0;reg<4;++reg) {
        int row = blockRow + wm*32 + mf*16 + q4*4 + reg;
        float v = acc[mf][nf][reg] + bb;
        if (RELU) v = fmaxf(v, 0.f);
        size_t oi = (size_t)row*CDIM + col;
        if (ACCUM)       ((float*)Cv)[oi] += v;
        else if (OUTBF16) ((short*)Cv)[oi] = f2bs(v);
        else              ((float*)Cv)[oi] = v;
      }
    }
}

// ---------------- MFMA flash attention, all-bf16 I/O ----------------
// grid (16, H, B), 256 thr = 4 waves; wave = 2 q-tiles of 16 rows.
// exp via exp2f(dot * C^-0.5*log2e) -- no clamp needed (|logit| <= ~0.3 for this model,
// exp2 overflow at 128; inputs finite so sum>0 always).
#define KS_STRIDE 40   // shorts: 80B rows, b128-aligned, balanced
#define VT_STRIDE 68   // shorts: 136B rows, b64-aligned; d0-group bank bases {0,16} = 2-way (free)
__global__ __launch_bounds__(256) void k_attn3(const short* __restrict__ Q,
    const short* __restrict__ K, const short* __restrict__ V, short* __restrict__ O) {
  __shared__ __align__(16) short Ks[64*KS_STRIDE];
  __shared__ __align__(16) short Vt[32*VT_STRIDE];
  const int tid = threadIdx.x;
  const int w = tid >> 6, lane = tid & 63;
  const int q4 = lane >> 4, r = lane & 15;
  const int b = blockIdx.z, h = blockIdx.y;
  const int rowbase = blockIdx.x*128 + w*32;
  const float lc = 0.0901684400056f;   // 2^-4 * log2(e)
  short8v Qf[2];
  #pragma unroll
  for (int u=0; u<2; ++u)
    Qf[u] = *(const short8v*)&Q[((size_t)(b*TDIM + rowbase + u*16 + r))*CDIM + h*HSZ + q4*8];
  float4v o00 = {0,0,0,0}, o01 = {0,0,0,0}, o10 = {0,0,0,0}, o11 = {0,0,0,0};
  float l0 = 0.f, l1 = 0.f;
  const int skey = tid >> 2, d0 = (tid & 3)*8;
  for (int s0 = 0; s0 < TDIM; s0 += 64) {
    __syncthreads();
    {
      size_t gidx = ((size_t)(b*TDIM + s0 + skey))*CDIM + h*HSZ + d0;
      *(short8v*)&Ks[skey*KS_STRIDE + d0] = *(const short8v*)&K[gidx];
      short8v vvv = *(const short8v*)&V[gidx];
      #pragma unroll
      for (int j=0;j<8;++j) Vt[(d0+j)*VT_STRIDE + skey] = vvv[j];
    }
    __syncthreads();
    #pragma unroll
    for (int ks = 0; ks < 4; ++ks) {
      short8v Kf = *(const short8v*)&Ks[(ks*16 + r)*KS_STRIDE + q4*8];
      float4v s0v = mfma32(Kf, Qf[0], (float4v){0,0,0,0});
      float4v s1v = mfma32(Kf, Qf[1], (float4v){0,0,0,0});
      short4v Vf0 = *(const short4v*)&Vt[r*VT_STRIDE + ks*16 + q4*4];
      short4v Vf1 = *(const short4v*)&Vt[(16+r)*VT_STRIDE + ks*16 + q4*4];
      float p00 = exp2f(s0v[0]*lc), p01 = exp2f(s0v[1]*lc);
      float p02 = exp2f(s0v[2]*lc), p03 = exp2f(s0v[3]*lc);
      float p10 = exp2f(s1v[0]*lc), p11 = exp2f(s1v[1]*lc);
      float p12 = exp2f(s1v[2]*lc), p13 = exp2f(s1v[3]*lc);
      l0 += (p00+p01) + (p02+p03);
      l1 += (p10+p11) + (p12+p13);
      union { unsigned u[2]; short4v s; } P0, P1;
      P0.u[0] = pkbf(p00, p01); P0.u[1] = pkbf(p02, p03);
      P1.u[0] = pkbf(p10, p11); P1.u[1] = pkbf(p12, p13);
      o00 = mfma16(P0.s, Vf0, o00); o01 = mfma16(P0.s, Vf1, o01);
      o10 = mfma16(P1.s, Vf0, o10); o11 = mfma16(P1.s, Vf1, o11);
    }
  }
  l0 += __shfl_xor(l0, 16, 64); l0 += __shfl_xor(l0, 32, 64);
  l1 += __shfl_xor(l1, 16, 64); l1 += __shfl_xor(l1, 32, 64);
  #pragma unroll
  for (int reg=0; reg<4; ++reg) {
    int qrow = q4*4 + reg;
    float i0 = 1.f / __shfl(l0, qrow, 64);
    float i1 = 1.f / __shfl(l1, qrow, 64);
    short* op0 = O + ((size_t)(b*TDIM + rowbase + qrow))*CDIM + h*HSZ;
    op0[r]    = f2bs(o00[reg]*i0);
    op0[16+r] = f2bs(o01[reg]*i0);
    short* op1 = O + ((size_t)(b*TDIM + rowbase + 16 + qrow))*CDIM + h*HSZ;
    op1[r]    = f2bs(o10[reg]*i1);
    op1[16+r] = f2bs(o11[reg]*i1);
  }
}

// ---------------- mean-pool partials (bf16 in) ----------------
__global__ __launch_bounds__(256) void k_pool(const short* __restrict__ Hf, float* __restrict__ part) {
  int b = blockIdx.x >> 3, chunk = blockIdx.x & 7;
  int c = threadIdx.x;
  int row0 = b*TDIM + chunk*256;
  float s = 0.f;
  for (int tt=0; tt<256; ++tt) s += bs2f(Hf[(size_t)(row0+tt)*CDIM + c]);
  part[blockIdx.x*256 + c] = s * (1.f/2048.f);
}

// ---------------- classifier ----------------
__global__ __launch_bounds__(256) void k_cls(const float* __restrict__ part,
    const float* __restrict__ Wc1, const float* __restrict__ bc1,
    const float* __restrict__ Wc2, const float* __restrict__ bc2, float* __restrict__ out) {
  __shared__ float se[4*256];
  __shared__ float sh[4*512];
  __shared__ float sl[40];
  int tid = threadIdx.x;
  for (int j=tid; j<1024; j+=256) {
    int b = j >> 8, c = j & 255;
    float s = 0.f;
    #pragma unroll
    for (int ch=0; ch<8; ++ch) s += part[(b*8+ch)*256 + c];
    se[j] = s;
  }
  __syncthreads();
  for (int j=tid; j<2048; j+=256) {
    int b = j >> 9, u = j & 511;
    float s = bc1[u];
    for (int c=0; c<256; ++c) s = fmaf(se[b*256+c], Wc1[c*512+u], s);
    sh[j] = fmaxf(s, 0.f);
  }
  __syncthreads();
  if (tid < 40) {
    int b = tid/10, j2 = tid%10;
    float s = bc2[j2];
    for (int u=0; u<512; ++u) s = fmaf(sh[b*512+u], Wc2[u*10+j2], s);
    sl[tid] = s;
  }
  __syncthreads();
  if (tid < 4) {
    float mx = -1e30f;
    for (int j=0;j<10;++j) mx = fmaxf(mx, sl[tid*10+j]);
    float e[10], sum = 0.f;
    for (int j=0;j<10;++j) { e[j] = __expf(sl[tid*10+j]-mx); sum += e[j]; }
    float inv = 1.f/sum;
    for (int j=0;j<10;++j) out[tid*10+j] = e[j]*inv;
  }
}

extern "C" void kernel_launch(void* const* d_in, const int* in_sizes, int n_in,
                              void* d_out, int out_size, void* d_ws, size_t ws_size,
                              hipStream_t stream) {
  const int*   idx = (const int*)d_in[0];
  const float* tok = (const float*)d_in[1];
  const float* pos = (const float*)d_in[2];
  const float* Wq  = (const float*)d_in[3];
  const float* Wk  = (const float*)d_in[4];
  const float* Wv  = (const float*)d_in[5];
  const float* Wp  = (const float*)d_in[6];
  const float* bp  = (const float*)d_in[7];
  const float* l1g = (const float*)d_in[8];
  const float* l1b = (const float*)d_in[9];
  const float* l2g = (const float*)d_in[10];
  const float* l2b = (const float*)d_in[11];
  const float* W1  = (const float*)d_in[12];
  const float* b1  = (const float*)d_in[13];
  const float* W2  = (const float*)d_in[14];
  const float* b2  = (const float*)d_in[15];
  const float* lfg = (const float*)d_in[16];
  const float* lfb = (const float*)d_in[17];
  const float* Wc1 = (const float*)d_in[18];
  const float* bc1 = (const float*)d_in[19];
  const float* Wc2 = (const float*)d_in[20];
  const float* bc2 = (const float*)d_in[21];

  float* xb  = (float*)d_ws;              // fp32 residual stream (8 MB)
  short* hb  = (short*)(xb + BUF);        // bf16 LN out / attn out (4 MB)
  short* qb  = hb + BUF;                  // bf16 Q / FFN hidden
  short* kb  = qb + BUF;                  // bf16 K
  short* vb  = kb + BUF;                  // bf16 V
  float* part = (float*)(vb + BUF);       // 32x256 pool partials

  dim3 gg(128, 2);                        // 64x128 tiles over [8192,256]
  k_embed<<<NTOK*CDIM/256, 256, 0, stream>>>(idx, tok, pos, xb);
  for (int l = 0; l < LNUM; ++l) {
    k_ln<<<NTOK, 256, 0, stream>>>(xb, l1g + l*CDIM, l1b + l*CDIM, hb);
    k_gemm2<1,false,false,true,false><<<gg, 256, 0, stream>>>(hb, Wq + l*65536, nullptr, qb);
    k_gemm2<1,false,false,true,false><<<gg, 256, 0, stream>>>(hb, Wk + l*65536, nullptr, kb);
    k_gemm2<1,false,false,true,false><<<gg, 256, 0, stream>>>(hb, Wv + l*65536, nullptr, vb);
    k_attn3<<<dim3(16, HDIM, BDIM), 256, 0, stream>>>(qb, kb, vb, hb);
    k_gemm2<0,true,false,false,true><<<gg, 256, 0, stream>>>(hb, Wp + l*65536, bp + l*CDIM, xb);
    k_ln<<<NTOK, 256, 0, stream>>>(xb, l2g + l*CDIM, l2b + l*CDIM, hb);
    k_gemm2<0,true,true,true,false><<<gg, 256, 0, stream>>>(hb, W1 + l*65536, b1 + l*CDIM, qb);
    k_gemm2<0,true,false,false,true><<<gg, 256, 0, stream>>>(qb, W2 + l*65536, b2 + l*CDIM, xb);
  }
  k_ln<<<NTOK, 256, 0, stream>>>(xb, lfg, lfb, hb);
  k_pool<<<32, 256, 0, stream>>>(hb, part);
  k_cls<<<1, 256, 0, stream>>>(part, Wc1, bc1, Wc2, bc2, (float*)d_out);
}

// Round 7
// 668.898 us; speedup vs baseline: 4.0800x; 1.1381x over previous
//
#include <hip/hip_runtime.h>
#include <hip/hip_bf16.h>

#define NTOK 8192      // B*T
#define CDIM 256
#define TDIM 2048
#define BDIM 4
#define HDIM 8
#define HSZ  32
#define LNUM 4
#define BUF  (NTOK*CDIM)
#define QSTR 768       // fused qkv row stride

typedef __attribute__((ext_vector_type(8))) short short8v;
typedef __attribute__((ext_vector_type(4))) short short4v;
typedef __attribute__((ext_vector_type(4))) float float4v;

// fp32 -> bf16 (RNE) as raw short
static __device__ __forceinline__ short f2bs(float f){
  union { float f; unsigned u; } x; x.f = f;
  unsigned r = x.u + 0x7FFFu + ((x.u >> 16) & 1u);
  return (short)(r >> 16);
}
static __device__ __forceinline__ float bs2f(short s){
  union { unsigned u; float f; } x; x.u = ((unsigned)(unsigned short)s) << 16;
  return x.f;
}
// pack two fp32 -> bf16x2 (RNE)
static __device__ __forceinline__ unsigned pkbf(float a, float b){
  union { float f; unsigned u; } x, y; x.f = a; y.f = b;
  unsigned ra = x.u + 0x7FFFu + ((x.u >> 16) & 1u);
  unsigned rb = y.u + 0x7FFFu + ((y.u >> 16) & 1u);
  return __builtin_amdgcn_perm(rb, ra, 0x07060302u);
}
// native exp2
#if __has_builtin(__builtin_amdgcn_exp2f)
static __device__ __forceinline__ float fexp2(float x){ return __builtin_amdgcn_exp2f(x); }
#else
static __device__ __forceinline__ float fexp2(float x){ return __expf(x*0.6931471805599453f); }
#endif

#if __has_builtin(__builtin_amdgcn_mfma_f32_16x16x16bf16_1k)
static __device__ __forceinline__ float4v mfma16(short4v a, short4v b, float4v c){
  return __builtin_amdgcn_mfma_f32_16x16x16bf16_1k(a, b, c, 0, 0, 0);
}
#else
static __device__ __forceinline__ float4v mfma16(short4v a, short4v b, float4v c){
  float4v d;
  asm volatile("v_mfma_f32_16x16x16_bf16 %0, %1, %2, %3\n\ts_nop 7\n\ts_nop 7"
               : "=v"(d) : "v"(a), "v"(b), "v"(c));
  return d;
}
#endif
static __device__ __forceinline__ float4v mfma32(short8v a, short8v b, float4v c){
  return __builtin_amdgcn_mfma_f32_16x16x32_bf16(a, b, c, 0, 0, 0);
}

// ---------------- weight prep: fp32 [K][N] (or QKV [H][K][32]) -> bf16 [N][K] ----------------
// 96 tiles/layer: 48 QKV (12 n-tiles x 4 k-tiles into [768][256]) + 3 x 16 for Wp/W1/W2.
__global__ __launch_bounds__(256) void k_prep(
    const float* __restrict__ Wq, const float* __restrict__ Wk, const float* __restrict__ Wv,
    const float* __restrict__ Wp, const float* __restrict__ W1, const float* __restrict__ W2,
    short* __restrict__ qkvT, short* __restrict__ wpT, short* __restrict__ w1T, short* __restrict__ w2T) {
  __shared__ float tile[64][65];
  const int tid = threadIdx.x;
  int id = blockIdx.x;
  int l = id / 96, rr = id % 96;
  const float* src; short* dst; int n0, k0; bool qkvmode;
  if (rr < 48) {
    int tn = rr >> 2, tk = rr & 3;
    n0 = tn*64; k0 = tk*64;
    const float* b3 = (n0 < 256) ? Wq : (n0 < 512 ? Wk : Wv);
    src = b3 + l*65536;
    dst = qkvT + (size_t)l*QSTR*256;
    qkvmode = true;
  } else {
    int r2 = rr - 48;
    int mat = r2 >> 4, t = r2 & 15;
    int tn = t >> 2, tk = t & 3;
    n0 = tn*64; k0 = tk*64;
    const float* b3 = (mat == 0) ? Wp : (mat == 1 ? W1 : W2);
    src = b3 + l*65536;
    dst = (mat == 0 ? wpT : (mat == 1 ? w1T : w2T)) + l*65536;
    qkvmode = false;
  }
  const int cn = tid & 63, rk = tid >> 6;
  #pragma unroll
  for (int i = 0; i < 16; ++i) {
    int kk = rk + i*4;
    int n = n0 + cn, k = k0 + kk;
    float v;
    if (qkvmode) { int nn = n & 255; v = src[((nn>>5)*256 + k)*32 + (nn & 31)]; }
    else         { v = src[k*256 + n]; }
    tile[kk][cn] = v;
  }
  __syncthreads();
  #pragma unroll
  for (int i = 0; i < 16; ++i) {
    int nn = rk + i*4;
    dst[(size_t)(n0 + nn)*256 + k0 + cn] = f2bs(tile[cn][nn]);
  }
}

// ---------------- embedding: fp32 residual stream ----------------
__global__ __launch_bounds__(256) void k_embed(const int* __restrict__ idx,
    const float* __restrict__ tok, const float* __restrict__ pos, float* __restrict__ x) {
  int i  = blockIdx.x*256 + threadIdx.x;
  int c  = i & (CDIM-1);
  int bt = i >> 8;
  int t  = bt & (TDIM-1);
  x[i] = tok[(size_t)idx[bt]*CDIM + c] + pos[t*CDIM + c];
}

// ---------------- layernorm: fp32 in -> bf16 out ----------------
__global__ __launch_bounds__(256) void k_ln(const float* __restrict__ X,
    const float* __restrict__ g, const float* __restrict__ b, short* __restrict__ Y) {
  int row = blockIdx.x, tid = threadIdx.x;
  float v = X[(size_t)row*CDIM + tid];
  float s1 = v, s2 = v*v;
  #pragma unroll
  for (int off=32; off>0; off>>=1) { s1 += __shfl_down(s1, off, 64); s2 += __shfl_down(s2, off, 64); }
  __shared__ float r1[4], r2[4];
  int wave = tid >> 6, lane = tid & 63;
  if (lane == 0) { r1[wave] = s1; r2[wave] = s2; }
  __syncthreads();
  s1 = r1[0]+r1[1]+r1[2]+r1[3];
  s2 = r2[0]+r2[1]+r2[2]+r2[3];
  float mean = s1*(1.f/CDIM);
  float var  = s2*(1.f/CDIM) - mean*mean;
  float inv  = rsqrtf(var + 1e-5f);
  Y[(size_t)row*CDIM + tid] = f2bs((v-mean)*inv*g[tid] + b[tid]);
}

// ---------------- LDS-free MFMA GEMM: C[8192,N] = A[8192,256](bf16) x Bt[N][256](bf16) ----------
// 1 wave/block, wave tile 32x64 (2 m-frags x 4 n-frags), K fully unrolled (8x32).
// Frag layouts (verified rounds 5/6): A[m=r][k=q4*8+j]; B[k=q4*8+j][n=r] (from Bt[n][k]);
// D: row=q4*4+reg, col=r.
template<bool BIAS, bool RELU, bool OUTBF16, bool ACCUM>
__global__ __launch_bounds__(64) void k_gemm3(const short* __restrict__ A,
    const short* __restrict__ Bt, const float* __restrict__ bias, void* __restrict__ Cv,
    int outstride) {
  const int lane = threadIdx.x;
  const int q4 = lane >> 4, r = lane & 15;
  const int blockRow = blockIdx.x * 32;
  const int blockCol = blockIdx.y * 64;
  float4v acc[2][4];
  #pragma unroll
  for (int i=0;i<2;++i)
    #pragma unroll
    for (int j=0;j<4;++j) acc[i][j] = (float4v){0,0,0,0};
  #pragma unroll
  for (int k0 = 0; k0 < 256; k0 += 32) {
    short8v a0 = *(const short8v*)&A[(size_t)(blockRow +      r)*CDIM + k0 + q4*8];
    short8v a1 = *(const short8v*)&A[(size_t)(blockRow + 16 + r)*CDIM + k0 + q4*8];
    #pragma unroll
    for (int nf=0; nf<4; ++nf) {
      short8v bf = *(const short8v*)&Bt[(size_t)(blockCol + nf*16 + r)*256 + k0 + q4*8];
      acc[0][nf] = mfma32(a0, bf, acc[0][nf]);
      acc[1][nf] = mfma32(a1, bf, acc[1][nf]);
    }
  }
  #pragma unroll
  for (int mf=0; mf<2; ++mf)
    #pragma unroll
    for (int nf=0; nf<4; ++nf) {
      int col = blockCol + nf*16 + r;
      float bb = BIAS ? bias[col] : 0.f;
      #pragma unroll
      for (int reg=0; reg<4; ++reg) {
        int row = blockRow + mf*16 + q4*4 + reg;
        float v = acc[mf][nf][reg] + bb;
        if (RELU) v = fmaxf(v, 0.f);
        size_t oi = (size_t)row*outstride + col;
        if (ACCUM)        ((float*)Cv)[oi] += v;
        else if (OUTBF16) ((short*)Cv)[oi] = f2bs(v);
        else              ((float*)Cv)[oi] = v;
      }
    }
}

// ---------------- MFMA flash attention, fused-QKV input, 8 waves x 16 q-rows ----------------
// grid (16, H, B), 512 thr; block covers 128 q-rows; waves 0-3 stage K, 4-7 stage V.
#define KS_STRIDE 40
#define VT_STRIDE 68
__global__ __launch_bounds__(512) void k_attn4(const short* __restrict__ qkv,
    short* __restrict__ O) {
  __shared__ __align__(16) short Ks[64*KS_STRIDE];
  __shared__ __align__(16) short Vt[32*VT_STRIDE];
  const int tid = threadIdx.x;
  const int w = tid >> 6, lane = tid & 63;
  const int q4 = lane >> 4, r = lane & 15;
  const int b = blockIdx.z, h = blockIdx.y;
  const int rowbase = blockIdx.x*128 + w*16;
  const float lc = 0.0901684400056f;   // 2^-4 * log2(e)
  short8v Qf = *(const short8v*)&qkv[((size_t)(b*TDIM + rowbase + r))*QSTR + h*HSZ + q4*8];
  float4v o0 = {0,0,0,0}, o1 = {0,0,0,0};
  float l0 = 0.f;
  const bool isV = tid >= 256;
  const int t2 = tid & 255;
  const int skey = t2 >> 2, d0 = (t2 & 3)*8;
  const int srcoff = isV ? (2*CDIM) : CDIM;   // K at +256, V at +512
  for (int s0 = 0; s0 < TDIM; s0 += 64) {
    __syncthreads();
    {
      short8v vv = *(const short8v*)&qkv[((size_t)(b*TDIM + s0 + skey))*QSTR + srcoff + h*HSZ + d0];
      if (isV) {
        #pragma unroll
        for (int j=0;j<8;++j) Vt[(d0+j)*VT_STRIDE + skey] = vv[j];
      } else {
        *(short8v*)&Ks[skey*KS_STRIDE + d0] = vv;
      }
    }
    __syncthreads();
    #pragma unroll
    for (int ks = 0; ks < 4; ++ks) {
      short8v Kf = *(const short8v*)&Ks[(ks*16 + r)*KS_STRIDE + q4*8];
      float4v sv = mfma32(Kf, Qf, (float4v){0,0,0,0});
      short4v Vf0 = *(const short4v*)&Vt[r*VT_STRIDE + ks*16 + q4*4];
      short4v Vf1 = *(const short4v*)&Vt[(16+r)*VT_STRIDE + ks*16 + q4*4];
      float p0 = fexp2(sv[0]*lc), p1 = fexp2(sv[1]*lc);
      float p2 = fexp2(sv[2]*lc), p3 = fexp2(sv[3]*lc);
      l0 += (p0+p1) + (p2+p3);
      union { unsigned u[2]; short4v s; } P;
      P.u[0] = pkbf(p0, p1); P.u[1] = pkbf(p2, p3);
      o0 = mfma16(P.s, Vf0, o0);
      o1 = mfma16(P.s, Vf1, o1);
    }
  }
  l0 += __shfl_xor(l0, 16, 64); l0 += __shfl_xor(l0, 32, 64);
  #pragma unroll
  for (int reg=0; reg<4; ++reg) {
    int qrow = q4*4 + reg;
    float i0 = 1.f / __shfl(l0, qrow, 64);
    short* op = O + ((size_t)(b*TDIM + rowbase + qrow))*CDIM + h*HSZ;
    op[r]    = f2bs(o0[reg]*i0);
    op[16+r] = f2bs(o1[reg]*i0);
  }
}

// ---------------- mean-pool partials (bf16 in) ----------------
__global__ __launch_bounds__(256) void k_pool(const short* __restrict__ Hf, float* __restrict__ part) {
  int b = blockIdx.x >> 3, chunk = blockIdx.x & 7;
  int c = threadIdx.x;
  int row0 = b*TDIM + chunk*256;
  float s = 0.f;
  for (int tt=0; tt<256; ++tt) s += bs2f(Hf[(size_t)(row0+tt)*CDIM + c]);
  part[blockIdx.x*256 + c] = s * (1.f/2048.f);
}

// ---------------- classifier ----------------
__global__ __launch_bounds__(256) void k_cls(const float* __restrict__ part,
    const float* __restrict__ Wc1, const float* __restrict__ bc1,
    const float* __restrict__ Wc2, const float* __restrict__ bc2, float* __restrict__ out) {
  __shared__ float se[4*256];
  __shared__ float sh[4*512];
  __shared__ float sl[40];
  int tid = threadIdx.x;
  for (int j=tid; j<1024; j+=256) {
    int b = j >> 8, c = j & 255;
    float s = 0.f;
    #pragma unroll
    for (int ch=0; ch<8; ++ch) s += part[(b*8+ch)*256 + c];
    se[j] = s;
  }
  __syncthreads();
  for (int j=tid; j<2048; j+=256) {
    int b = j >> 9, u = j & 511;
    float s = bc1[u];
    for (int c=0; c<256; ++c) s = fmaf(se[b*256+c], Wc1[c*512+u], s);
    sh[j] = fmaxf(s, 0.f);
  }
  __syncthreads();
  if (tid < 40) {
    int b = tid/10, j2 = tid%10;
    float s = bc2[j2];
    for (int u=0; u<512; ++u) s = fmaf(sh[b*512+u], Wc2[u*10+j2], s);
    sl[tid] = s;
  }
  __syncthreads();
  if (tid < 4) {
    float mx = -1e30f;
    for (int j=0;j<10;++j) mx = fmaxf(mx, sl[tid*10+j]);
    float e[10], sum = 0.f;
    for (int j=0;j<10;++j) { e[j] = __expf(sl[tid*10+j]-mx); sum += e[j]; }
    float inv = 1.f/sum;
    for (int j=0;j<10;++j) out[tid*10+j] = e[j]*inv;
  }
}

extern "C" void kernel_launch(void* const* d_in, const int* in_sizes, int n_in,
                              void* d_out, int out_size, void* d_ws, size_t ws_size,
                              hipStream_t stream) {
  const int*   idx = (const int*)d_in[0];
  const float* tok = (const float*)d_in[1];
  const float* pos = (const float*)d_in[2];
  const float* Wq  = (const float*)d_in[3];
  const float* Wk  = (const float*)d_in[4];
  const float* Wv  = (const float*)d_in[5];
  const float* Wp  = (const float*)d_in[6];
  const float* bp  = (const float*)d_in[7];
  const float* l1g = (const float*)d_in[8];
  const float* l1b = (const float*)d_in[9];
  const float* l2g = (const float*)d_in[10];
  const float* l2b = (const float*)d_in[11];
  const float* W1  = (const float*)d_in[12];
  const float* b1  = (const float*)d_in[13];
  const float* W2  = (const float*)d_in[14];
  const float* b2  = (const float*)d_in[15];
  const float* lfg = (const float*)d_in[16];
  const float* lfb = (const float*)d_in[17];
  const float* Wc1 = (const float*)d_in[18];
  const float* bc1 = (const float*)d_in[19];
  const float* Wc2 = (const float*)d_in[20];
  const float* bc2 = (const float*)d_in[21];

  char* p = (char*)d_ws;
  float* xb   = (float*)p;              p += (size_t)BUF*4;        // fp32 residual (8 MB)
  short* hb   = (short*)p;              p += (size_t)BUF*2;        // bf16 LN/attn out (4 MB)
  short* qkvb = (short*)p;              p += (size_t)NTOK*QSTR*2;  // bf16 fused QKV (12 MB)
  float* part = (float*)p;              p += 32*256*4;
  short* wqkvT = (short*)p;             p += (size_t)LNUM*QSTR*256*2;  // 1.5 MB
  short* wpT   = (short*)p;             p += (size_t)LNUM*65536*2;
  short* w1T   = (short*)p;             p += (size_t)LNUM*65536*2;
  short* w2T   = (short*)p;             p += (size_t)LNUM*65536*2;
  short* fh    = qkvb;                  // FFN hidden reuses qkv buffer

  k_prep<<<384, 256, 0, stream>>>(Wq, Wk, Wv, Wp, W1, W2, wqkvT, wpT, w1T, w2T);
  k_embed<<<NTOK*CDIM/256, 256, 0, stream>>>(idx, tok, pos, xb);
  for (int l = 0; l < LNUM; ++l) {
    k_ln<<<NTOK, 256, 0, stream>>>(xb, l1g + l*CDIM, l1b + l*CDIM, hb);
    k_gemm3<false,false,true,false><<<dim3(256,12), 64, 0, stream>>>(
        hb, wqkvT + (size_t)l*QSTR*256, nullptr, qkvb, QSTR);
    k_attn4<<<dim3(16, HDIM, BDIM), 512, 0, stream>>>(qkvb, hb);
    k_gemm3<true,false,false,true><<<dim3(256,4), 64, 0, stream>>>(
        hb, wpT + (size_t)l*65536, bp + l*CDIM, xb, CDIM);
    k_ln<<<NTOK, 256, 0, stream>>>(xb, l2g + l*CDIM, l2b + l*CDIM, hb);
    k_gemm3<true,true,true,false><<<dim3(256,4), 64, 0, stream>>>(
        hb, w1T + (size_t)l*65536, b1 + l*CDIM, fh, CDIM);
    k_gemm3<true,false,false,true><<<dim3(256,4), 64, 0, stream>>>(
        fh, w2T + (size_t)l*65536, b2 + l*CDIM, xb, CDIM);
  }
  k_ln<<<NTOK, 256, 0, stream>>>(xb, lfg, lfb, hb);
  k_pool<<<32, 256, 0, stream>>>(hb, part);
  k_cls<<<1, 256, 0, stream>>>(part, Wc1, bc1, Wc2, bc2, (float*)d_out);
}

// Round 8
// 580.860 us; speedup vs baseline: 4.6984x; 1.1516x over previous
//
#include <hip/hip_runtime.h>
#include <hip/hip_bf16.h>

#define NTOK 8192      // B*T
#define CDIM 256
#define TDIM 2048
#define BDIM 4
#define HDIM 8
#define HSZ  32
#define LNUM 4
#define BUF  (NTOK*CDIM)
#define QSTR 768       // fused qkv row stride

typedef __attribute__((ext_vector_type(8))) short short8v;
typedef __attribute__((ext_vector_type(4))) short short4v;
typedef __attribute__((ext_vector_type(4))) float float4v;

// fp32 -> bf16 (RNE) as raw short
static __device__ __forceinline__ short f2bs(float f){
  union { float f; unsigned u; } x; x.f = f;
  unsigned r = x.u + 0x7FFFu + ((x.u >> 16) & 1u);
  return (short)(r >> 16);
}
static __device__ __forceinline__ float bs2f(short s){
  union { unsigned u; float f; } x; x.u = ((unsigned)(unsigned short)s) << 16;
  return x.f;
}
// pack two fp32 -> bf16x2 (RNE); result low half = a, high half = b
static __device__ __forceinline__ unsigned pkbf(float a, float b){
  union { float f; unsigned u; } x, y; x.f = a; y.f = b;
  unsigned ra = x.u + 0x7FFFu + ((x.u >> 16) & 1u);
  unsigned rb = y.u + 0x7FFFu + ((y.u >> 16) & 1u);
  return __builtin_amdgcn_perm(rb, ra, 0x07060302u);
}
#if __has_builtin(__builtin_amdgcn_exp2f)
static __device__ __forceinline__ float fexp2(float x){ return __builtin_amdgcn_exp2f(x); }
#else
static __device__ __forceinline__ float fexp2(float x){ return __expf(x*0.6931471805599453f); }
#endif

#if __has_builtin(__builtin_amdgcn_mfma_f32_16x16x16bf16_1k)
static __device__ __forceinline__ float4v mfma16(short4v a, short4v b, float4v c){
  return __builtin_amdgcn_mfma_f32_16x16x16bf16_1k(a, b, c, 0, 0, 0);
}
#else
static __device__ __forceinline__ float4v mfma16(short4v a, short4v b, float4v c){
  float4v d;
  asm volatile("v_mfma_f32_16x16x16_bf16 %0, %1, %2, %3\n\ts_nop 7\n\ts_nop 7"
               : "=v"(d) : "v"(a), "v"(b), "v"(c));
  return d;
}
#endif
static __device__ __forceinline__ float4v mfma32(short8v a, short8v b, float4v c){
  return __builtin_amdgcn_mfma_f32_16x16x32_bf16(a, b, c, 0, 0, 0);
}

// ---------------- weight prep: fp32 [K][N] (or QKV [H][K][32]) -> bf16 [N][K] ----------------
__global__ __launch_bounds__(256) void k_prep(
    const float* __restrict__ Wq, const float* __restrict__ Wk, const float* __restrict__ Wv,
    const float* __restrict__ Wp, const float* __restrict__ W1, const float* __restrict__ W2,
    short* __restrict__ qkvT, short* __restrict__ wpT, short* __restrict__ w1T, short* __restrict__ w2T) {
  __shared__ float tile[64][65];
  const int tid = threadIdx.x;
  int id = blockIdx.x;
  int l = id / 96, rr = id % 96;
  const float* src; short* dst; int n0, k0; bool qkvmode;
  if (rr < 48) {
    int tn = rr >> 2, tk = rr & 3;
    n0 = tn*64; k0 = tk*64;
    const float* b3 = (n0 < 256) ? Wq : (n0 < 512 ? Wk : Wv);
    src = b3 + l*65536;
    dst = qkvT + (size_t)l*QSTR*256;
    qkvmode = true;
  } else {
    int r2 = rr - 48;
    int mat = r2 >> 4, t = r2 & 15;
    int tn = t >> 2, tk = t & 3;
    n0 = tn*64; k0 = tk*64;
    const float* b3 = (mat == 0) ? Wp : (mat == 1 ? W1 : W2);
    src = b3 + l*65536;
    dst = (mat == 0 ? wpT : (mat == 1 ? w1T : w2T)) + l*65536;
    qkvmode = false;
  }
  const int cn = tid & 63, rk = tid >> 6;
  #pragma unroll
  for (int i = 0; i < 16; ++i) {
    int kk = rk + i*4;
    int n = n0 + cn, k = k0 + kk;
    float v;
    if (qkvmode) { int nn = n & 255; v = src[((nn>>5)*256 + k)*32 + (nn & 31)]; }
    else         { v = src[k*256 + n]; }
    tile[kk][cn] = v;
  }
  __syncthreads();
  #pragma unroll
  for (int i = 0; i < 16; ++i) {
    int nn = rk + i*4;
    dst[(size_t)(n0 + nn)*256 + k0 + cn] = f2bs(tile[cn][nn]);
  }
}

// ---------------- embedding: float4-vectorized, wave covers one token row ----------------
__global__ __launch_bounds__(256) void k_embed(const int* __restrict__ idx,
    const float* __restrict__ tok, const float* __restrict__ pos, float* __restrict__ x) {
  int i  = blockIdx.x*256 + threadIdx.x;      // over NTOK*CDIM/4
  int c4 = (i & 63) * 4;
  int bt = i >> 6;
  int t  = bt & (TDIM-1);
  float4 tv = *(const float4*)&tok[(size_t)idx[bt]*CDIM + c4];
  float4 pv = *(const float4*)&pos[(size_t)t*CDIM + c4];
  *(float4*)&x[(size_t)bt*CDIM + c4] =
      make_float4(tv.x+pv.x, tv.y+pv.y, tv.z+pv.z, tv.w+pv.w);
}

// ---------------- layernorm: wave per row, no LDS/barrier ----------------
__global__ __launch_bounds__(256) void k_ln(const float* __restrict__ X,
    const float* __restrict__ g, const float* __restrict__ b, short* __restrict__ Y) {
  const int lane = threadIdx.x & 63;
  const int row = blockIdx.x*4 + (threadIdx.x >> 6);
  float4 v = *(const float4*)&X[(size_t)row*CDIM + lane*4];
  float s1 = (v.x+v.y) + (v.z+v.w);
  float s2 = (v.x*v.x + v.y*v.y) + (v.z*v.z + v.w*v.w);
  #pragma unroll
  for (int off=32; off>0; off>>=1) { s1 += __shfl_xor(s1, off, 64); s2 += __shfl_xor(s2, off, 64); }
  float mean = s1*(1.f/CDIM);
  float var  = s2*(1.f/CDIM) - mean*mean;
  float inv  = rsqrtf(var + 1e-5f);
  float4 gv = *(const float4*)&g[lane*4];
  float4 bv = *(const float4*)&b[lane*4];
  union { unsigned u[2]; short4v s; } o;
  o.u[0] = pkbf((v.x-mean)*inv*gv.x + bv.x, (v.y-mean)*inv*gv.y + bv.y);
  o.u[1] = pkbf((v.z-mean)*inv*gv.z + bv.z, (v.w-mean)*inv*gv.w + bv.w);
  *(short4v*)&Y[(size_t)row*CDIM + lane*4] = o.s;
}

// ---------------- LDS-free MFMA GEMM: C[8192,NF*16*gridy] = A(bf16) x Bt[N][256](bf16) --------
// 1 wave/block, wave tile 32 x (NF*16). Frag layouts verified rounds 5/6.
template<int NF, bool BIAS, bool RELU, bool OUTBF16, bool ACCUM>
__global__ __launch_bounds__(64) void k_gemm3(const short* __restrict__ A,
    const short* __restrict__ Bt, const float* __restrict__ bias, void* __restrict__ Cv,
    int outstride) {
  const int lane = threadIdx.x;
  const int q4 = lane >> 4, r = lane & 15;
  const int blockRow = blockIdx.x * 32;
  const int blockCol = blockIdx.y * (NF*16);
  float4v acc[2][NF];
  #pragma unroll
  for (int i=0;i<2;++i)
    #pragma unroll
    for (int j=0;j<NF;++j) acc[i][j] = (float4v){0,0,0,0};
  #pragma unroll
  for (int k0 = 0; k0 < 256; k0 += 32) {
    short8v a0 = *(const short8v*)&A[(size_t)(blockRow +      r)*CDIM + k0 + q4*8];
    short8v a1 = *(const short8v*)&A[(size_t)(blockRow + 16 + r)*CDIM + k0 + q4*8];
    #pragma unroll
    for (int nf=0; nf<NF; ++nf) {
      short8v bf = *(const short8v*)&Bt[(size_t)(blockCol + nf*16 + r)*256 + k0 + q4*8];
      acc[0][nf] = mfma32(a0, bf, acc[0][nf]);
      acc[1][nf] = mfma32(a1, bf, acc[1][nf]);
    }
  }
  #pragma unroll
  for (int mf=0; mf<2; ++mf)
    #pragma unroll
    for (int nf=0; nf<NF; ++nf) {
      int col = blockCol + nf*16 + r;
      float bb = BIAS ? bias[col] : 0.f;
      #pragma unroll
      for (int reg=0; reg<4; ++reg) {
        int row = blockRow + mf*16 + q4*4 + reg;
        float v = acc[mf][nf][reg] + bb;
        if (RELU) v = fmaxf(v, 0.f);
        size_t oi = (size_t)row*outstride + col;
        if (ACCUM)        ((float*)Cv)[oi] += v;
        else if (OUTBF16) ((short*)Cv)[oi] = f2bs(v);
        else              ((float*)Cv)[oi] = v;
      }
    }
}

// ---------------- MFMA flash attention, fused-QKV input, 8 waves x 16 q-rows ----------------
#define KS_STRIDE 40
#define VT_STRIDE 68
__global__ __launch_bounds__(512) void k_attn4(const short* __restrict__ qkv,
    short* __restrict__ O) {
  __shared__ __align__(16) short Ks[64*KS_STRIDE];
  __shared__ __align__(16) short Vt[32*VT_STRIDE];
  const int tid = threadIdx.x;
  const int w = tid >> 6, lane = tid & 63;
  const int q4 = lane >> 4, r = lane & 15;
  const int b = blockIdx.z, h = blockIdx.y;
  const int rowbase = blockIdx.x*128 + w*16;
  const float lc = 0.0901684400056f;   // 2^-4 * log2(e)
  short8v Qf = *(const short8v*)&qkv[((size_t)(b*TDIM + rowbase + r))*QSTR + h*HSZ + q4*8];
  float4v o0 = {0,0,0,0}, o1 = {0,0,0,0};
  float l0 = 0.f;
  const bool isV = tid >= 256;
  const int t2 = tid & 255;
  const int skey = t2 >> 2, d0 = (t2 & 3)*8;
  const int srcoff = isV ? (2*CDIM) : CDIM;
  for (int s0 = 0; s0 < TDIM; s0 += 64) {
    __syncthreads();
    {
      short8v vv = *(const short8v*)&qkv[((size_t)(b*TDIM + s0 + skey))*QSTR + srcoff + h*HSZ + d0];
      if (isV) {
        #pragma unroll
        for (int j=0;j<8;++j) Vt[(d0+j)*VT_STRIDE + skey] = vv[j];
      } else {
        *(short8v*)&Ks[skey*KS_STRIDE + d0] = vv;
      }
    }
    __syncthreads();
    #pragma unroll
    for (int ks = 0; ks < 4; ++ks) {
      short8v Kf = *(const short8v*)&Ks[(ks*16 + r)*KS_STRIDE + q4*8];
      float4v sv = mfma32(Kf, Qf, (float4v){0,0,0,0});
      short4v Vf0 = *(const short4v*)&Vt[r*VT_STRIDE + ks*16 + q4*4];
      short4v Vf1 = *(const short4v*)&Vt[(16+r)*VT_STRIDE + ks*16 + q4*4];
      float p0 = fexp2(sv[0]*lc), p1 = fexp2(sv[1]*lc);
      float p2 = fexp2(sv[2]*lc), p3 = fexp2(sv[3]*lc);
      l0 += (p0+p1) + (p2+p3);
      union { unsigned u[2]; short4v s; } P;
      P.u[0] = pkbf(p0, p1); P.u[1] = pkbf(p2, p3);
      o0 = mfma16(P.s, Vf0, o0);
      o1 = mfma16(P.s, Vf1, o1);
    }
  }
  l0 += __shfl_xor(l0, 16, 64); l0 += __shfl_xor(l0, 32, 64);
  #pragma unroll
  for (int reg=0; reg<4; ++reg) {
    int qrow = q4*4 + reg;
    float i0 = 1.f / __shfl(l0, qrow, 64);
    short* op = O + ((size_t)(b*TDIM + rowbase + qrow))*CDIM + h*HSZ;
    op[r]    = f2bs(o0[reg]*i0);
    op[16+r] = f2bs(o1[reg]*i0);
  }
}

// ---------------- mean-pool partials: vectorized short4 reads ----------------
__global__ __launch_bounds__(256) void k_pool(const short* __restrict__ Hf, float* __restrict__ part) {
  __shared__ float red[4][256];
  int b = blockIdx.x >> 3, chunk = blockIdx.x & 7;
  int c4 = (threadIdx.x & 63) * 4, rg = threadIdx.x >> 6;
  int row0 = b*TDIM + chunk*256 + rg*64;
  float s[4] = {0,0,0,0};
  for (int tt=0; tt<64; ++tt) {
    short4v v = *(const short4v*)&Hf[(size_t)(row0+tt)*CDIM + c4];
    s[0]+=bs2f(v[0]); s[1]+=bs2f(v[1]); s[2]+=bs2f(v[2]); s[3]+=bs2f(v[3]);
  }
  #pragma unroll
  for (int j=0;j<4;++j) red[rg][c4+j] = s[j];
  __syncthreads();
  int c = threadIdx.x;
  part[blockIdx.x*256 + c] =
      (red[0][c]+red[1][c]+red[2][c]+red[3][c]) * (1.f/2048.f);
}

// ---------------- classifier stage 1: combine partials + fc1 + relu ----------------
// grid (2, 4): blockIdx.x = u-chunk of 256, blockIdx.y = batch; coalesced Wc1 reads.
__global__ __launch_bounds__(256) void k_cls1(const float* __restrict__ part,
    const float* __restrict__ Wc1, const float* __restrict__ bc1, float* __restrict__ hid) {
  __shared__ float se[256];
  const int b = blockIdx.y;
  const int u = blockIdx.x*256 + threadIdx.x;
  const int c = threadIdx.x;
  float s = 0.f;
  #pragma unroll
  for (int ch=0; ch<8; ++ch) s += part[(b*8+ch)*256 + c];
  se[c] = s;
  __syncthreads();
  float acc = bc1[u];
  #pragma unroll 16
  for (int c2=0; c2<256; ++c2) acc = fmaf(se[c2], Wc1[c2*512 + u], acc);
  hid[b*512 + u] = fmaxf(acc, 0.f);
}

// ---------------- classifier stage 2: fc2 + softmax ----------------
__global__ __launch_bounds__(256) void k_cls2(const float* __restrict__ hid,
    const float* __restrict__ Wc2, const float* __restrict__ bc2, float* __restrict__ out) {
  __shared__ float red[160];
  __shared__ float sl[40];
  const int t = threadIdx.x;
  if (t < 160) {
    int o = t >> 2, pp = t & 3;
    int b = o / 10, j = o - b*10;
    const float* hp = hid + b*512 + pp*128;
    float s = 0.f;
    #pragma unroll 8
    for (int u=0; u<128; ++u) s = fmaf(hp[u], Wc2[(pp*128+u)*10 + j], s);
    red[t] = s;
  }
  __syncthreads();
  if (t < 40) sl[t] = (red[t*4]+red[t*4+1]) + (red[t*4+2]+red[t*4+3]) + bc2[t%10];
  __syncthreads();
  if (t < 4) {
    float mx = -1e30f;
    for (int j=0;j<10;++j) mx = fmaxf(mx, sl[t*10+j]);
    float e[10], sum = 0.f;
    for (int j=0;j<10;++j) { e[j] = __expf(sl[t*10+j]-mx); sum += e[j]; }
    float inv = 1.f/sum;
    for (int j=0;j<10;++j) out[t*10+j] = e[j]*inv;
  }
}

extern "C" void kernel_launch(void* const* d_in, const int* in_sizes, int n_in,
                              void* d_out, int out_size, void* d_ws, size_t ws_size,
                              hipStream_t stream) {
  const int*   idx = (const int*)d_in[0];
  const float* tok = (const float*)d_in[1];
  const float* pos = (const float*)d_in[2];
  const float* Wq  = (const float*)d_in[3];
  const float* Wk  = (const float*)d_in[4];
  const float* Wv  = (const float*)d_in[5];
  const float* Wp  = (const float*)d_in[6];
  const float* bp  = (const float*)d_in[7];
  const float* l1g = (const float*)d_in[8];
  const float* l1b = (const float*)d_in[9];
  const float* l2g = (const float*)d_in[10];
  const float* l2b = (const float*)d_in[11];
  const float* W1  = (const float*)d_in[12];
  const float* b1  = (const float*)d_in[13];
  const float* W2  = (const float*)d_in[14];
  const float* b2  = (const float*)d_in[15];
  const float* lfg = (const float*)d_in[16];
  const float* lfb = (const float*)d_in[17];
  const float* Wc1 = (const float*)d_in[18];
  const float* bc1 = (const float*)d_in[19];
  const float* Wc2 = (const float*)d_in[20];
  const float* bc2 = (const float*)d_in[21];

  char* p = (char*)d_ws;
  float* xb   = (float*)p;              p += (size_t)BUF*4;        // fp32 residual (8 MB)
  short* hb   = (short*)p;              p += (size_t)BUF*2;        // bf16 LN/attn out (4 MB)
  short* qkvb = (short*)p;              p += (size_t)NTOK*QSTR*2;  // bf16 fused QKV (12 MB)
  float* part = (float*)p;              p += 32*256*4;
  float* hid  = (float*)p;              p += 4*512*4;
  short* wqkvT = (short*)p;             p += (size_t)LNUM*QSTR*256*2;
  short* wpT   = (short*)p;             p += (size_t)LNUM*65536*2;
  short* w1T   = (short*)p;             p += (size_t)LNUM*65536*2;
  short* w2T   = (short*)p;             p += (size_t)LNUM*65536*2;
  short* fh    = qkvb;                  // FFN hidden reuses qkv buffer

  k_prep<<<384, 256, 0, stream>>>(Wq, Wk, Wv, Wp, W1, W2, wqkvT, wpT, w1T, w2T);
  k_embed<<<NTOK*CDIM/1024, 256, 0, stream>>>(idx, tok, pos, xb);
  for (int l = 0; l < LNUM; ++l) {
    k_ln<<<NTOK/4, 256, 0, stream>>>(xb, l1g + l*CDIM, l1b + l*CDIM, hb);
    k_gemm3<4,false,false,true,false><<<dim3(256,12), 64, 0, stream>>>(
        hb, wqkvT + (size_t)l*QSTR*256, nullptr, qkvb, QSTR);
    k_attn4<<<dim3(16, HDIM, BDIM), 512, 0, stream>>>(qkvb, hb);
    k_gemm3<2,true,false,false,true><<<dim3(256,8), 64, 0, stream>>>(
        hb, wpT + (size_t)l*65536, bp + l*CDIM, xb, CDIM);
    k_ln<<<NTOK/4, 256, 0, stream>>>(xb, l2g + l*CDIM, l2b + l*CDIM, hb);
    k_gemm3<2,true,true,true,false><<<dim3(256,8), 64, 0, stream>>>(
        hb, w1T + (size_t)l*65536, b1 + l*CDIM, fh, CDIM);
    k_gemm3<2,true,false,false,true><<<dim3(256,8), 64, 0, stream>>>(
        fh, w2T + (size_t)l*65536, b2 + l*CDIM, xb, CDIM);
  }
  k_ln<<<NTOK/4, 256, 0, stream>>>(xb, lfg, lfb, hb);
  k_pool<<<32, 256, 0, stream>>>(hb, part);
  k_cls1<<<dim3(2,4), 256, 0, stream>>>(part, Wc1, bc1, hid);
  k_cls2<<<1, 256, 0, stream>>>(hid, Wc2, bc2, (float*)d_out);
}